// Round 19
// baseline (227.613 us; speedup 1.0000x reference)
//
#include <hip/hip_runtime.h>
#include <math.h>
#include <stdint.h>

#define H 512
#define W 512
#define NPIX (H * W)          // 262144
#define NB 2
#define NF 180
#define KS 17
#define WSCALE 1024.0f        // exact power of two; cancels in both outputs

#define RAW_U32 1360          // raw rows 17*80 (also aliased by epilogue scratch)
#define BCH_U32 3072          // one K-chunk of weights (hi+lo, 192 filters), 12 KB

typedef _Float16 half8 __attribute__((ext_vector_type(8)));
typedef float floatx16 __attribute__((ext_vector_type(16)));
typedef uint32_t u32x4 __attribute__((ext_vector_type(4)));

union FragU { u32x4 u; half8 h; };

// ---------------- taps (match numpy float64 _gauss1d) ----------------
__global__ void k_taps(float* __restrict__ taps) {
  if (threadIdx.x == 0 && blockIdx.x == 0) {
    {
      double k[5], s = 0.0;
      for (int i = 0; i < 5; i++) { double xv = (double)(i - 2) / 0.4; k[i] = exp(-0.5 * xv * xv); s += k[i]; }
      for (int i = 0; i < 5; i++) taps[i] = (float)(k[i] / s);
    }
    {
      double k[81], s = 0.0;
      for (int i = 0; i < 81; i++) { double xv = (double)(i - 40) / 10.0; k[i] = exp(-0.5 * xv * xv); s += k[i]; }
      for (int i = 0; i < 81; i++) taps[8 + i] = (float)(k[i] / s);
    }
  }
}

// ---------------- weight repack into MFMA fragment order, f16 split ----------------
// Bf (u32): chunk c (19): [c*3072 ..]: hi frags: t*256 + lane*4 + q ; lo at +1536
// W[m][k]: m = t*32 + (lane&31) (filter), k = 8*(lane>>5) + j, dword q: j=2q lo16, j=2q+1 hi16
// chunks: c<17: (ky=c, kx=k); c==17: (ky=k, kx=16); c==18: k==0 -> (ky=16,kx=16)
__global__ void k_repackB(const float* __restrict__ w, uint32_t* __restrict__ Bf) {
  int tid = blockIdx.x * 256 + threadIdx.x;
  if (tid >= 19 * 6 * 64 * 4) return;
  int q = tid & 3;
  int lane = (tid >> 2) & 63;
  int ct = tid >> 8;
  int t = ct % 6, c = ct / 6;
  int n = t * 32 + (lane & 31);
  int hf = lane >> 5;
  uint32_t hv = 0, lv = 0;
  for (int s = 0; s < 2; s++) {
    int j = 2 * q + s;
    int k = hf * 8 + j;   // 0..15
    float val = 0.f;
    if (n < NF) {
      if (c < 17)       val = w[n * 289 + c * 17 + k];
      else if (c == 17) val = w[n * 289 + k * 17 + 16];
      else if (k == 0)  val = w[n * 289 + 16 * 17 + 16];
    }
    val *= WSCALE;
    _Float16 hh = (_Float16)val;
    _Float16 ll = (_Float16)(val - (float)hh);
    hv |= (uint32_t)__builtin_bit_cast(uint16_t, hh) << (16 * s);
    lv |= (uint32_t)__builtin_bit_cast(uint16_t, ll) << (16 * s);
  }
  int base = c * 3072;
  int off = t * 256 + lane * 4 + q;
  Bf[base + off] = hv;
  Bf[base + 1536 + off] = lv;
}

// ---------------- gray ----------------
__global__ void k_gray(const float* __restrict__ x, float* __restrict__ gray) {
  int i = blockIdx.x * blockDim.x + threadIdx.x;
  if (i >= NB * NPIX) return;
  int b = i / NPIX, r = i % NPIX;
  const float* xb = x + (size_t)b * 3 * NPIX;
  gray[i] = 0.2989f * xb[r] + 0.587f * xb[NPIX + r] + 0.114f * xb[2 * NPIX + r];
}

// ---------------- vertical blur, both sigmas fused ----------------
__global__ void k_vblur2(const float* __restrict__ in, float* __restrict__ outA,
                         float* __restrict__ outB, const float* __restrict__ taps) {
  int i = blockIdx.x * blockDim.x + threadIdx.x;
  if (i >= NB * NPIX) return;
  int b = i / NPIX, r = i % NPIX;
  int y = r / W, xx = r % W;
  const float* img = in + (size_t)b * NPIX;
  float a = 0.f;
#pragma unroll
  for (int j = -2; j <= 2; j++) {
    int yy = y + j; yy = yy < 0 ? 0 : (yy > H - 1 ? H - 1 : yy);
    a = fmaf(taps[j + 2], img[yy * W + xx], a);
  }
  float c = 0.f;
  for (int j = -40; j <= 40; j++) {
    int yy = y + j; yy = yy < 0 ? 0 : (yy > H - 1 ? H - 1 : yy);
    c = fmaf(taps[8 + j + 40], img[yy * W + xx], c);
  }
  outA[i] = a;
  outB[i] = c;
}

// ---------------- horizontal blur + DoG + f16-split pack ----------------
__global__ void k_hblur_dog(const float* __restrict__ inA, const float* __restrict__ inB,
                            uint32_t* __restrict__ dogp, const float* __restrict__ taps) {
  int i = blockIdx.x * blockDim.x + threadIdx.x;
  if (i >= NB * NPIX) return;
  int b = i / NPIX, r = i % NPIX;
  int y = r / W, xx = r % W;
  const float* ra = inA + (size_t)b * NPIX + (size_t)y * W;
  const float* rb = inB + (size_t)b * NPIX + (size_t)y * W;
  float a = 0.f;
#pragma unroll
  for (int j = -2; j <= 2; j++) {
    int xc = xx + j; xc = xc < 0 ? 0 : (xc > W - 1 ? W - 1 : xc);
    a = fmaf(taps[j + 2], ra[xc], a);
  }
  float c = 0.f;
  for (int j = -40; j <= 40; j++) {
    int xc = xx + j; xc = xc < 0 ? 0 : (xc > W - 1 ? W - 1 : xc);
    c = fmaf(taps[8 + j + 40], rb[xc], c);
  }
  float d = a - c;
  _Float16 hh = (_Float16)d;
  _Float16 ll = (_Float16)(d - (float)hh);
  dogp[i] = ((uint32_t)__builtin_bit_cast(uint16_t, ll) << 16) |
            (uint32_t)__builtin_bit_cast(uint16_t, hh);
}

// ---------------- main: TRANSPOSED implicit-GEMM, 1-row waves, 3 waves/SIMD ----------------
// block: 256 thr = 4 waves; w: fg=w&1 (filter group), ch=w>>1 (col half).
// wave: 1 row x 32 cols x 96 filters -> acc 48 regs; total ~140 -> 3 waves/SIMD.
// W-frags direct from global (Bf 233 KB, L2-resident), register double-buffered;
// barrier-free main loop. Only LDS: read-only raw tile + epilogue scratch.
__launch_bounds__(256, 3)
__global__ void k_conv(const uint32_t* __restrict__ dogp,
                       const uint32_t* __restrict__ Bf,
                       const float* __restrict__ bins,
                       float* __restrict__ out) {
  __shared__ uint32_t pool[RAW_U32];

  const int b  = blockIdx.z;
  const int y0 = blockIdx.y;          // one output row per block
  const int x0 = blockIdx.x * 64;
  const int tid = threadIdx.x;
  const int lane = tid & 63;
  const int w  = __builtin_amdgcn_readfirstlane(tid >> 6);  // 0..3
  const int fg  = w & 1;          // filter group (tiles 3fg .. 3fg+2)
  const int ch  = w >> 1;         // col half
  const int nl = lane & 31;
  const int half = lane >> 5;

  // ---- stage raw rows y0-8 .. y0+8 (17), cols x0-8 .. x0+71 (zero-padded) ----
  const uint32_t* dgb = dogp + (size_t)b * NPIX;
  for (int i = tid; i < 17 * 80; i += 256) {
    int ry = i / 80, rx = i % 80;
    int gy = y0 + ry - 8, gx = x0 + rx - 8;
    uint32_t v = 0;
    if (gy >= 0 && gy < H && gx >= 0 && gx < W) v = dgb[gy * W + gx];
    pool[i] = v;
  }
  __syncthreads();

  floatx16 acc[3];   // [filter tile t within group]
#pragma unroll
  for (int t = 0; t < 3; t++)
#pragma unroll
    for (int q = 0; q < 16; q++) acc[t][q] = 0.f;

  const int abase = ch * 32 + nl + half * 8;

  // build data fragment (hi/lo) for staged row tr
  auto buildRow = [&](int tr, FragU& fh, FragU& fl) {
    const uint32_t* rp = &pool[tr * 80 + abase];
    uint32_t d[8];
#pragma unroll
    for (int j = 0; j < 8; j++) d[j] = rp[j];
#pragma unroll
    for (int q = 0; q < 4; q++) {
      fh.u[q] = __builtin_amdgcn_perm(d[2 * q + 1], d[2 * q], 0x05040100u);
      fl.u[q] = __builtin_amdgcn_perm(d[2 * q + 1], d[2 * q], 0x07060302u);
    }
  };
  // build data strip fragment for tail chunk c (17/18)
  auto buildStrip = [&](int c, FragU& fh, FragU& fl) {
    int kyb = (c - 17) * 16 + half * 8;
    uint32_t d[8];
#pragma unroll
    for (int j = 0; j < 8; j++) {
      int ky = kyb + j; if (ky > 16) ky = 16;   // clamped reads killed by W=0
      d[j] = pool[ky * 80 + ch * 32 + nl + 16];
    }
#pragma unroll
    for (int q = 0; q < 4; q++) {
      fh.u[q] = __builtin_amdgcn_perm(d[2 * q + 1], d[2 * q], 0x05040100u);
      fl.u[q] = __builtin_amdgcn_perm(d[2 * q + 1], d[2 * q], 0x07060302u);
    }
  };
  // 9 MFMAs on current W-frags; product order per acc: Wh*Dh, Wh*Dl, Wl*Dh
  auto mfma9 = [&](FragU* wh, FragU* wl, FragU& dh, FragU& dl) {
#pragma unroll
    for (int t = 0; t < 3; t++)
      acc[t] = __builtin_amdgcn_mfma_f32_32x32x16_f16(wh[t].h, dh.h, acc[t], 0, 0, 0);
#pragma unroll
    for (int t = 0; t < 3; t++)
      acc[t] = __builtin_amdgcn_mfma_f32_32x32x16_f16(wh[t].h, dl.h, acc[t], 0, 0, 0);
#pragma unroll
    for (int t = 0; t < 3; t++)
      acc[t] = __builtin_amdgcn_mfma_f32_32x32x16_f16(wl[t].h, dh.h, acc[t], 0, 0, 0);
  };

  // W-fragment pointers for this wave's filter group (global, L2-hot)
  const uint32_t* wbh = Bf + (size_t)(3 * fg) * 256 + (size_t)lane * 4;
  const uint32_t* wbl = wbh + 1536;

  FragU wch[3], wcl[3], wnh[3], wnl2[3];
#pragma unroll
  for (int t = 0; t < 3; t++) {
    wch[t].u = *(const u32x4*)(wbh + t * 256);
    wcl[t].u = *(const u32x4*)(wbl + t * 256);
  }

  FragU ah, al;

  // row chunks 0..16 (chunk c uses staged row c) — NO barriers
#pragma unroll
  for (int c = 0; c < 17; c++) {
    // prefetch next chunk's W-frags (chunk c+1; c+1 <= 17)
    const uint32_t* nbh = wbh + (size_t)(c + 1) * BCH_U32;
    const uint32_t* nbl = wbl + (size_t)(c + 1) * BCH_U32;
#pragma unroll
    for (int t = 0; t < 3; t++) {
      wnh[t].u  = *(const u32x4*)(nbh + t * 256);
      wnl2[t].u = *(const u32x4*)(nbl + t * 256);
    }
    buildRow(c, ah, al);
    mfma9(wch, wcl, ah, al);
#pragma unroll
    for (int t = 0; t < 3; t++) { wch[t] = wnh[t]; wcl[t] = wnl2[t]; }
  }
  // chunk 17 (strip kx=16, ky=k 0..15); prefetch chunk 18
  {
    const uint32_t* nbh = wbh + (size_t)18 * BCH_U32;
    const uint32_t* nbl = wbl + (size_t)18 * BCH_U32;
#pragma unroll
    for (int t = 0; t < 3; t++) {
      wnh[t].u  = *(const u32x4*)(nbh + t * 256);
      wnl2[t].u = *(const u32x4*)(nbl + t * 256);
    }
    FragU sh, sl;
    buildStrip(17, sh, sl);
    mfma9(wch, wcl, sh, sl);
#pragma unroll
    for (int t = 0; t < 3; t++) { wch[t] = wnh[t]; wcl[t] = wnl2[t]; }
  }
  // chunk 18 (strip tap ky=16,kx=16)
  {
    FragU sh, sl;
    buildStrip(18, sh, sl);
    mfma9(wch, wcl, sh, sl);
  }
  __syncthreads();   // waves drift in the barrier-free loop; raw tile dead now

  // ---- epilogue: lane-local per group, LDS merge across fg ----
  float* pm = (float*)&pool[0];      // [fg(2)][64]
  int*   pn = (int*)&pool[128];
  float* pS = (float*)&pool[256];
  float* pc = (float*)&pool[384];
  int*   fn = (int*)&pool[512];      // [64]
  float* fS = (float*)&pool[576];

  const float PI_F = 3.14159265358979323846f;
  const float INV_PI = 0.31830988618379067154f;
  const double STEPD = 3.14159265358979323846 * 179.0 / 180.0 / 179.0;
  const float stepf = (float)STEPD;
  const float hbase = (4.0f * (float)half) * stepf;
  const int colp = ch * 32 + nl;

  // stage 1: lane-local argmax/sum over this wave's 48 filters, half-merged
  {
    float m = -1.f; int n = 0; float S0 = 0.f, S1 = 0.f;
#pragma unroll
    for (int t = 0; t < 3; t++) {
#pragma unroll
      for (int q = 0; q < 16; q++) {
        float v = fabsf(acc[t][q]);
        if (q & 1) S1 += v; else S0 += v;
        int nf = 32 * (3 * fg + t) + (q & 3) + 8 * (q >> 2) + 4 * half;
        if (v > m) { m = v; n = nf; }
      }
    }
    float S = S0 + S1;
    float mo = __shfl_xor(m, 32);
    int   no = __shfl_xor(n, 32);
    float So = __shfl_xor(S, 32);
    bool take = (mo > m) || (mo == m && no < n);
    if (take) { m = mo; n = no; }
    S += So;
    if (half == 0) {
      int o = fg * 64 + colp;
      pm[o] = m; pn[o] = n; pS[o] = S;
    }
  }
  __syncthreads();

  // stage 2: fg==0 waves combine groups, write orientation
  if (fg == 0) {
    int o0 = 0 * 64 + colp;
    int o1 = 1 * 64 + colp;
    float m0 = pm[o0], m1 = pm[o1];
    int n = (m1 > m0) ? pn[o1] : pn[o0];   // strict > keeps smaller index on tie
    float S = pS[o0] + pS[o1];
    float om = (float)n / 180.0f * 255.0f;
    if (half == 0) {
      fn[colp] = n; fS[colp] = S;
      out[(size_t)b * NPIX + (size_t)y0 * W + x0 + colp] = om;
    }
  }
  __syncthreads();

  // stage 3: all waves, partial confidence with the final winner
  {
    int nwin = fn[colp];
    float om = (float)nwin / 180.0f * 255.0f;
    float rad = om / 180.0f * PI_F;
    float ddc = rad - hbase;
    float C0 = 0.f, C1 = 0.f;
#pragma unroll
    for (int t = 0; t < 3; t++) {
#pragma unroll
      for (int q = 0; q < 16; q++) {
        const float K = (float)((double)(32 * (3 * fg + t) + (q & 3) + 8 * (q >> 2)) * STEPD);
        float dd = ddc - K;
        float r = rintf(dd * INV_PI);
        float dist = fmaf(-PI_F, r, dd);
        float w2 = dist * dist;
        if (q & 1) C1 = fmaf(w2, fabsf(acc[t][q]), C1);
        else       C0 = fmaf(w2, fabsf(acc[t][q]), C0);
      }
    }
    float C = C0 + C1;
    C += __shfl_xor(C, 32);
    if (half == 0) pc[fg * 64 + colp] = C;
  }
  __syncthreads();

  // stage 4: fg==0 waves finalize confidence
  if (fg == 0) {
    float C = pc[0 * 64 + colp] + pc[1 * 64 + colp];
    if (half == 0) {
      out[(size_t)NB * NPIX + (size_t)b * NPIX + (size_t)y0 * W + x0 + colp]
          = C / fS[colp];
    }
  }
}

extern "C" void kernel_launch(void* const* d_in, const int* in_sizes, int n_in,
                              void* d_out, int out_size, void* d_ws, size_t ws_size,
                              hipStream_t stream) {
  const float* x = (const float*)d_in[0];      // [2,3,512,512]
  const float* wts = (const float*)d_in[1];    // [180,1,17,17]
  const float* bins = (const float*)d_in[2];   // [180]
  float* out = (float*)d_out;

  float* ws = (float*)d_ws;
  float* gray = ws;                                 // 524288 f32
  float* tmpA = ws + (size_t)NB * NPIX;             // 524288 f32
  float* tmpB = tmpA + (size_t)NB * NPIX;           // 524288 f32
  uint32_t* dogp = (uint32_t*)(tmpB + (size_t)NB * NPIX);  // 524288 u32
  float* taps = (float*)(dogp + (size_t)NB * NPIX); // 128 f32
  uint32_t* Bf = (uint32_t*)(taps + 128);           // 19*3072 u32

  k_taps<<<1, 64, 0, stream>>>(taps);
  k_repackB<<<114, 256, 0, stream>>>(wts, Bf);

  int n = NB * NPIX;
  int blk = 256, grd = (n + blk - 1) / blk;
  k_gray<<<grd, blk, 0, stream>>>(x, gray);
  k_vblur2<<<grd, blk, 0, stream>>>(gray, tmpA, tmpB, taps);
  k_hblur_dog<<<grd, blk, 0, stream>>>(tmpA, tmpB, dogp, taps);

  dim3 g(W / 64, H, NB);
  k_conv<<<g, 256, 0, stream>>>(dogp, Bf, bins, out);
}

// Round 20
// 190.474 us; speedup vs baseline: 1.1950x; 1.1950x over previous
//
#include <hip/hip_runtime.h>
#include <math.h>
#include <stdint.h>

#define H 512
#define W 512
#define NPIX (H * W)          // 262144
#define NB 2
#define NF 180
#define KS 17
#define WSCALE 1024.0f        // exact power of two; cancels in both outputs

#define RAW_OFF 0             // raw packed rows: 18*80
#define HP_OFF  1440          // hi-pair plane: 18*80
#define LP_OFF  2880          // lo-pair plane: 18*80
#define POOL_U32 4320         // 17.3 KB
#define BCH_U32 3072          // one K-chunk of weights (hi+lo, 192 filters), 12 KB

typedef _Float16 half8 __attribute__((ext_vector_type(8)));
typedef float floatx16 __attribute__((ext_vector_type(16)));
typedef uint32_t u32x4 __attribute__((ext_vector_type(4)));

union FragU { u32x4 u; half8 h; };

// ---------------- taps (match numpy float64 _gauss1d) ----------------
__global__ void k_taps(float* __restrict__ taps) {
  if (threadIdx.x == 0 && blockIdx.x == 0) {
    {
      double k[5], s = 0.0;
      for (int i = 0; i < 5; i++) { double xv = (double)(i - 2) / 0.4; k[i] = exp(-0.5 * xv * xv); s += k[i]; }
      for (int i = 0; i < 5; i++) taps[i] = (float)(k[i] / s);
    }
    {
      double k[81], s = 0.0;
      for (int i = 0; i < 81; i++) { double xv = (double)(i - 40) / 10.0; k[i] = exp(-0.5 * xv * xv); s += k[i]; }
      for (int i = 0; i < 81; i++) taps[8 + i] = (float)(k[i] / s);
    }
  }
}

// ---------------- weight repack into MFMA fragment order, f16 split ----------------
// Bf (u32): chunk c (19): [c*3072 ..]: hi frags: t*256 + lane*4 + q ; lo at +1536
// W[m][k]: m = t*32 + (lane&31) (filter), k = 8*(lane>>5) + j, dword q: j=2q lo16, j=2q+1 hi16
// chunks: c<17: (ky=c, kx=k); c==17: (ky=k, kx=16); c==18: k==0 -> (ky=16,kx=16)
__global__ void k_repackB(const float* __restrict__ w, uint32_t* __restrict__ Bf) {
  int tid = blockIdx.x * 256 + threadIdx.x;
  if (tid >= 19 * 6 * 64 * 4) return;
  int q = tid & 3;
  int lane = (tid >> 2) & 63;
  int ct = tid >> 8;
  int t = ct % 6, c = ct / 6;
  int n = t * 32 + (lane & 31);
  int hf = lane >> 5;
  uint32_t hv = 0, lv = 0;
  for (int s = 0; s < 2; s++) {
    int j = 2 * q + s;
    int k = hf * 8 + j;   // 0..15
    float val = 0.f;
    if (n < NF) {
      if (c < 17)       val = w[n * 289 + c * 17 + k];
      else if (c == 17) val = w[n * 289 + k * 17 + 16];
      else if (k == 0)  val = w[n * 289 + 16 * 17 + 16];
    }
    val *= WSCALE;
    _Float16 hh = (_Float16)val;
    _Float16 ll = (_Float16)(val - (float)hh);
    hv |= (uint32_t)__builtin_bit_cast(uint16_t, hh) << (16 * s);
    lv |= (uint32_t)__builtin_bit_cast(uint16_t, ll) << (16 * s);
  }
  int base = c * 3072;
  int off = t * 256 + lane * 4 + q;
  Bf[base + off] = hv;
  Bf[base + 1536 + off] = lv;
}

// ---------------- gray ----------------
__global__ void k_gray(const float* __restrict__ x, float* __restrict__ gray) {
  int i = blockIdx.x * blockDim.x + threadIdx.x;
  if (i >= NB * NPIX) return;
  int b = i / NPIX, r = i % NPIX;
  const float* xb = x + (size_t)b * 3 * NPIX;
  gray[i] = 0.2989f * xb[r] + 0.587f * xb[NPIX + r] + 0.114f * xb[2 * NPIX + r];
}

// ---------------- vertical blur, both sigmas fused ----------------
__global__ void k_vblur2(const float* __restrict__ in, float* __restrict__ outA,
                         float* __restrict__ outB, const float* __restrict__ taps) {
  int i = blockIdx.x * blockDim.x + threadIdx.x;
  if (i >= NB * NPIX) return;
  int b = i / NPIX, r = i % NPIX;
  int y = r / W, xx = r % W;
  const float* img = in + (size_t)b * NPIX;
  float a = 0.f;
#pragma unroll
  for (int j = -2; j <= 2; j++) {
    int yy = y + j; yy = yy < 0 ? 0 : (yy > H - 1 ? H - 1 : yy);
    a = fmaf(taps[j + 2], img[yy * W + xx], a);
  }
  float c = 0.f;
  for (int j = -40; j <= 40; j++) {
    int yy = y + j; yy = yy < 0 ? 0 : (yy > H - 1 ? H - 1 : yy);
    c = fmaf(taps[8 + j + 40], img[yy * W + xx], c);
  }
  outA[i] = a;
  outB[i] = c;
}

// ---------------- horizontal blur + DoG + f16-split pack ----------------
__global__ void k_hblur_dog(const float* __restrict__ inA, const float* __restrict__ inB,
                            uint32_t* __restrict__ dogp, const float* __restrict__ taps) {
  int i = blockIdx.x * blockDim.x + threadIdx.x;
  if (i >= NB * NPIX) return;
  int b = i / NPIX, r = i % NPIX;
  int y = r / W, xx = r % W;
  const float* ra = inA + (size_t)b * NPIX + (size_t)y * W;
  const float* rb = inB + (size_t)b * NPIX + (size_t)y * W;
  float a = 0.f;
#pragma unroll
  for (int j = -2; j <= 2; j++) {
    int xc = xx + j; xc = xc < 0 ? 0 : (xc > W - 1 ? W - 1 : xc);
    a = fmaf(taps[j + 2], ra[xc], a);
  }
  float c = 0.f;
  for (int j = -40; j <= 40; j++) {
    int xc = xx + j; xc = xc < 0 ? 0 : (xc > W - 1 ? W - 1 : xc);
    c = fmaf(taps[8 + j + 40], rb[xc], c);
  }
  float d = a - c;
  _Float16 hh = (_Float16)d;
  _Float16 ll = (_Float16)(d - (float)hh);
  dogp[i] = ((uint32_t)__builtin_bit_cast(uint16_t, ll) << 16) |
            (uint32_t)__builtin_bit_cast(uint16_t, hh);
}

// ---------------- main: TRANSPOSED implicit-GEMM, barrier-free, pair-plane LDS ----------------
// block: 256 thr = 4 waves; w: fg=w&1 (filter group), ch=w>>1 (col half).
// wave: 2 rows x 32 cols x 96 filters (acc 96). W-frags direct from global
// (Bf 233 KB, L2-resident), register double-buffered; main loop FULLY UNROLLED
// (ping-pong copies become SSA renames). Data frags read from pre-permuted
// hi/lo pair planes in LDS (zero v_perm in the hot loop; bit-identical words).
__launch_bounds__(256, 2)
__global__ void k_conv(const uint32_t* __restrict__ dogp,
                       const uint32_t* __restrict__ Bf,
                       const float* __restrict__ bins,
                       float* __restrict__ out) {
  __shared__ uint32_t pool[POOL_U32];

  const int b  = blockIdx.z;
  const int y0 = blockIdx.y * 2;
  const int x0 = blockIdx.x * 64;
  const int tid = threadIdx.x;
  const int lane = tid & 63;
  const int w  = __builtin_amdgcn_readfirstlane(tid >> 6);  // 0..3
  const int fg  = w & 1;          // filter group (tiles 3fg .. 3fg+2)
  const int ch  = w >> 1;         // col half
  const int nl = lane & 31;
  const int half = lane >> 5;

  // ---- stage raw rows y0-8 .. y0+9 (18), cols x0-8 .. x0+71 (zero-padded) ----
  const uint32_t* dgb = dogp + (size_t)b * NPIX;
  for (int i = tid; i < 18 * 80; i += 256) {
    int ry = i / 80, rx = i % 80;
    int gy = y0 + ry - 8, gx = x0 + rx - 8;
    uint32_t v = 0;
    if (gy >= 0 && gy < H && gx >= 0 && gx < W) v = dgb[gy * W + gx];
    pool[RAW_OFF + i] = v;
  }
  __syncthreads();
  // ---- build pre-permuted pair planes (exactly the perms buildRow used) ----
  for (int i = tid; i < 18 * 80; i += 256) {
    int c = i % 80;
    uint32_t v0 = pool[RAW_OFF + i];
    uint32_t v1 = (c < 79) ? pool[RAW_OFF + i + 1] : 0u;
    pool[HP_OFF + i] = __builtin_amdgcn_perm(v1, v0, 0x05040100u);
    pool[LP_OFF + i] = __builtin_amdgcn_perm(v1, v0, 0x07060302u);
  }
  __syncthreads();

  floatx16 acc[2][3];   // [data row d][filter tile t within group]
#pragma unroll
  for (int d = 0; d < 2; d++)
#pragma unroll
    for (int t = 0; t < 3; t++)
#pragma unroll
      for (int q = 0; q < 16; q++) acc[d][t][q] = 0.f;

  const int abase = ch * 32 + nl + half * 8;

  // build data fragment (hi/lo) for tile row tr — pair-plane reads, no perms
  auto buildRow = [&](int tr, FragU& fh, FragU& fl) {
    const uint32_t* hp = &pool[HP_OFF + tr * 80 + abase];
    const uint32_t* lp = &pool[LP_OFF + tr * 80 + abase];
#pragma unroll
    for (int q = 0; q < 4; q++) {
      fh.u[q] = hp[2 * q];
      fl.u[q] = lp[2 * q];
    }
  };
  // build data strip fragment for tail chunk c (17/18), data row base rb (raw plane)
  auto buildStrip = [&](int c, int rb, FragU& fh, FragU& fl) {
    int kyb = (c - 17) * 16 + half * 8;
    uint32_t d[8];
#pragma unroll
    for (int j = 0; j < 8; j++) {
      int ky = kyb + j; if (ky > 16) ky = 16;   // clamped reads killed by W=0
      d[j] = pool[RAW_OFF + (rb + ky) * 80 + ch * 32 + nl + 16];
    }
#pragma unroll
    for (int q = 0; q < 4; q++) {
      fh.u[q] = __builtin_amdgcn_perm(d[2 * q + 1], d[2 * q], 0x05040100u);
      fl.u[q] = __builtin_amdgcn_perm(d[2 * q + 1], d[2 * q], 0x07060302u);
    }
  };
  // 18 MFMAs on current W-frags; product order per acc: Wh*Dh, Wh*Dl, Wl*Dh
  auto mfma18 = [&](FragU* wh, FragU* wl,
                    FragU& d0h, FragU& d0l, FragU& d1h, FragU& d1l) {
#pragma unroll
    for (int t = 0; t < 3; t++) {
      acc[0][t] = __builtin_amdgcn_mfma_f32_32x32x16_f16(wh[t].h, d0h.h, acc[0][t], 0, 0, 0);
      acc[1][t] = __builtin_amdgcn_mfma_f32_32x32x16_f16(wh[t].h, d1h.h, acc[1][t], 0, 0, 0);
    }
#pragma unroll
    for (int t = 0; t < 3; t++) {
      acc[0][t] = __builtin_amdgcn_mfma_f32_32x32x16_f16(wh[t].h, d0l.h, acc[0][t], 0, 0, 0);
      acc[1][t] = __builtin_amdgcn_mfma_f32_32x32x16_f16(wh[t].h, d1l.h, acc[1][t], 0, 0, 0);
    }
#pragma unroll
    for (int t = 0; t < 3; t++) {
      acc[0][t] = __builtin_amdgcn_mfma_f32_32x32x16_f16(wl[t].h, d0h.h, acc[0][t], 0, 0, 0);
      acc[1][t] = __builtin_amdgcn_mfma_f32_32x32x16_f16(wl[t].h, d1h.h, acc[1][t], 0, 0, 0);
    }
  };

  // W-fragment pointers for this wave's filter group (global, L2-hot)
  const uint32_t* wbh = Bf + (size_t)(3 * fg) * 256 + (size_t)lane * 4;
  const uint32_t* wbl = wbh + 1536;

  FragU wch[3], wcl[3], wnh[3], wnl2[3];
#pragma unroll
  for (int t = 0; t < 3; t++) {
    wch[t].u = *(const u32x4*)(wbh + t * 256);
    wcl[t].u = *(const u32x4*)(wbl + t * 256);
  }

  FragU a0h, a0l, a1h, a1l;
  buildRow(0, a0h, a0l);   // chunk 0, data row 0 (rolls forward)

  // row chunks 0..16 (chunk c uses data rows c, c+1) — NO barriers, FULL unroll
#pragma unroll
  for (int c = 0; c < 17; c++) {
    // prefetch next chunk's W-frags (chunk c+1; c+1 <= 17)
    const uint32_t* nbh = wbh + (size_t)(c + 1) * BCH_U32;
    const uint32_t* nbl = wbl + (size_t)(c + 1) * BCH_U32;
#pragma unroll
    for (int t = 0; t < 3; t++) {
      wnh[t].u  = *(const u32x4*)(nbh + t * 256);
      wnl2[t].u = *(const u32x4*)(nbl + t * 256);
    }
    buildRow(c + 1, a1h, a1l);
    mfma18(wch, wcl, a0h, a0l, a1h, a1l);
    a0h = a1h; a0l = a1l;
#pragma unroll
    for (int t = 0; t < 3; t++) { wch[t] = wnh[t]; wcl[t] = wnl2[t]; }
  }
  // chunk 17 (strip kx=16, ky=k 0..15); prefetch chunk 18
  {
    const uint32_t* nbh = wbh + (size_t)18 * BCH_U32;
    const uint32_t* nbl = wbl + (size_t)18 * BCH_U32;
#pragma unroll
    for (int t = 0; t < 3; t++) {
      wnh[t].u  = *(const u32x4*)(nbh + t * 256);
      wnl2[t].u = *(const u32x4*)(nbl + t * 256);
    }
    FragU s0h, s0l, s1h, s1l;
    buildStrip(17, 0, s0h, s0l);
    buildStrip(17, 1, s1h, s1l);
    mfma18(wch, wcl, s0h, s0l, s1h, s1l);
#pragma unroll
    for (int t = 0; t < 3; t++) { wch[t] = wnh[t]; wcl[t] = wnl2[t]; }
  }
  // chunk 18 (strip ky=16..)
  {
    FragU s0h, s0l, s1h, s1l;
    buildStrip(18, 0, s0h, s0l);
    buildStrip(18, 1, s1h, s1l);
    mfma18(wch, wcl, s0h, s0l, s1h, s1l);
  }
  __syncthreads();   // waves drift in the barrier-free loop; planes dead now

  // ---- epilogue: lane-local per group, LDS merge across fg ----
  float* pm = (float*)&pool[0];      // [d(2)][fg(2)][64]
  int*   pn = (int*)&pool[256];
  float* pS = (float*)&pool[512];
  float* pc = (float*)&pool[768];
  int*   fn = (int*)&pool[1024];     // [d(2)][64]
  float* fS = (float*)&pool[1152];

  const float PI_F = 3.14159265358979323846f;
  const float INV_PI = 0.31830988618379067154f;
  const double STEPD = 3.14159265358979323846 * 179.0 / 180.0 / 179.0;
  const float stepf = (float)STEPD;
  const float hbase = (4.0f * (float)half) * stepf;
  const int colp = ch * 32 + nl;

  // stage 1: per-wave lane-local argmax/sum over its 48 filters, half-merged
#pragma unroll
  for (int d = 0; d < 2; d++) {
    float m = -1.f; int n = 0; float S0 = 0.f, S1 = 0.f;
#pragma unroll
    for (int t = 0; t < 3; t++) {
#pragma unroll
      for (int q = 0; q < 16; q++) {
        float v = fabsf(acc[d][t][q]);
        if (q & 1) S1 += v; else S0 += v;
        int nf = 32 * (3 * fg + t) + (q & 3) + 8 * (q >> 2) + 4 * half;
        if (v > m) { m = v; n = nf; }
      }
    }
    float S = S0 + S1;
    float mo = __shfl_xor(m, 32);
    int   no = __shfl_xor(n, 32);
    float So = __shfl_xor(S, 32);
    bool take = (mo > m) || (mo == m && no < n);
    if (take) { m = mo; n = no; }
    S += So;
    if (half == 0) {
      int o = (d * 2 + fg) * 64 + colp;
      pm[o] = m; pn[o] = n; pS[o] = S;
    }
  }
  __syncthreads();

  // stage 2: fg==0 waves combine groups, write orientation
  if (fg == 0) {
#pragma unroll
    for (int d = 0; d < 2; d++) {
      int o0 = (d * 2 + 0) * 64 + colp;
      int o1 = (d * 2 + 1) * 64 + colp;
      float m0 = pm[o0], m1 = pm[o1];
      int n = (m1 > m0) ? pn[o1] : pn[o0];   // strict > keeps smaller index on tie
      float S = pS[o0] + pS[o1];
      float om = (float)n / 180.0f * 255.0f;
      if (half == 0) {
        fn[d * 64 + colp] = n; fS[d * 64 + colp] = S;
        out[(size_t)b * NPIX + (size_t)(y0 + d) * W + x0 + colp] = om;
      }
    }
  }
  __syncthreads();

  // stage 3: all waves, partial confidence with the final winner
#pragma unroll
  for (int d = 0; d < 2; d++) {
    int nwin = fn[d * 64 + colp];
    float om = (float)nwin / 180.0f * 255.0f;
    float rad = om / 180.0f * PI_F;
    float ddc = rad - hbase;
    float C0 = 0.f, C1 = 0.f;
#pragma unroll
    for (int t = 0; t < 3; t++) {
#pragma unroll
      for (int q = 0; q < 16; q++) {
        const float K = (float)((double)(32 * (3 * fg + t) + (q & 3) + 8 * (q >> 2)) * STEPD);
        float dd = ddc - K;
        float r = rintf(dd * INV_PI);
        float dist = fmaf(-PI_F, r, dd);
        float w2 = dist * dist;
        if (q & 1) C1 = fmaf(w2, fabsf(acc[d][t][q]), C1);
        else       C0 = fmaf(w2, fabsf(acc[d][t][q]), C0);
      }
    }
    float C = C0 + C1;
    C += __shfl_xor(C, 32);
    if (half == 0) pc[(d * 2 + fg) * 64 + colp] = C;
  }
  __syncthreads();

  // stage 4: fg==0 waves finalize confidence
  if (fg == 0) {
#pragma unroll
    for (int d = 0; d < 2; d++) {
      float C = pc[(d * 2 + 0) * 64 + colp] + pc[(d * 2 + 1) * 64 + colp];
      if (half == 0) {
        out[(size_t)NB * NPIX + (size_t)b * NPIX + (size_t)(y0 + d) * W + x0 + colp]
            = C / fS[d * 64 + colp];
      }
    }
  }
}

extern "C" void kernel_launch(void* const* d_in, const int* in_sizes, int n_in,
                              void* d_out, int out_size, void* d_ws, size_t ws_size,
                              hipStream_t stream) {
  const float* x = (const float*)d_in[0];      // [2,3,512,512]
  const float* wts = (const float*)d_in[1];    // [180,1,17,17]
  const float* bins = (const float*)d_in[2];   // [180]
  float* out = (float*)d_out;

  float* ws = (float*)d_ws;
  float* gray = ws;                                 // 524288 f32
  float* tmpA = ws + (size_t)NB * NPIX;             // 524288 f32
  float* tmpB = tmpA + (size_t)NB * NPIX;           // 524288 f32
  uint32_t* dogp = (uint32_t*)(tmpB + (size_t)NB * NPIX);  // 524288 u32
  float* taps = (float*)(dogp + (size_t)NB * NPIX); // 128 f32
  uint32_t* Bf = (uint32_t*)(taps + 128);           // 19*3072 u32

  k_taps<<<1, 64, 0, stream>>>(taps);
  k_repackB<<<114, 256, 0, stream>>>(wts, Bf);

  int n = NB * NPIX;
  int blk = 256, grd = (n + blk - 1) / blk;
  k_gray<<<grd, blk, 0, stream>>>(x, gray);
  k_vblur2<<<grd, blk, 0, stream>>>(gray, tmpA, tmpB, taps);
  k_hblur_dog<<<grd, blk, 0, stream>>>(tmpA, tmpB, dogp, taps);

  dim3 g(W / 64, H / 2, NB);
  k_conv<<<g, 256, 0, stream>>>(dogp, Bf, bins, out);
}